// Round 6
// baseline (272.428 us; speedup 1.0000x reference)
//
#include <hip/hip_runtime.h>
#include <hip/hip_bf16.h>

typedef __attribute__((ext_vector_type(8))) short short8;
typedef __attribute__((ext_vector_type(4))) short short4v;
typedef __attribute__((ext_vector_type(2))) int   int2v;
typedef __attribute__((ext_vector_type(4))) float floatx4;

#define BATCH 16
#define SEQ   2048
#define DIM   64
#define QSCALE 0.18033688011112042f   /* 0.125 * log2(e) : softmax in exp2 domain */
#define WS_NEED (12u*1024u*1024u)

__device__ __forceinline__ unsigned short f2bf(float f) {
    return __builtin_bit_cast(unsigned short, __float2bfloat16(f));
}

// raw v_exp_f32 (exp2). exp2f usually lowers to this, but guarantee it.
#if defined(__has_builtin)
#if __has_builtin(__builtin_amdgcn_exp2f)
#define EXP2(x) __builtin_amdgcn_exp2f(x)
#endif
#endif
#ifndef EXP2
#define EXP2(x) exp2f(x)
#endif

// ---- K=16 bf16 MFMA: prefer intrinsic, fall back to inline asm ----
#if defined(__has_builtin)
#if __has_builtin(__builtin_amdgcn_mfma_f32_16x16x16bf16_1k)
#define MFMA16(A,B,C) __builtin_amdgcn_mfma_f32_16x16x16bf16_1k(A,B,C,0,0,0)
#elif __has_builtin(__builtin_amdgcn_mfma_f32_16x16x16_bf16)
#define MFMA16(A,B,C) __builtin_amdgcn_mfma_f32_16x16x16_bf16(A,B,C,0,0,0)
#endif
#endif
#ifndef MFMA16
__device__ __forceinline__ floatx4 mfma16_asm(short4v a, short4v b, floatx4 c) {
    asm volatile("s_nop 1\n\tv_mfma_f32_16x16x16_bf16 %0, %1, %2, %0"
                 : "+v"(c) : "v"(a), "v"(b));
    return c;
}
#define MFMA16(A,B,C) mfma16_asm(A,B,C)
#endif

// ---------------- convert: fp32 -> bf16 MFMA-frag layouts ----------------
// Qw [16][128 t16][2 st][64 l][8p] = Q[b][t16*16+a][st*32+g*8+p] * QSCALE  (a=l&15,g=l>>4)
// Kw same (scale 1).
// Vw [16][128 kt][64 l][4 dt][4p] = V[b][kt*16+g*4+p][dt*16+a]   (B frag for 16x16x16)
__global__ __launch_bounds__(256)
void convert_kernel(const float* __restrict__ Q, const float* __restrict__ K,
                    const float* __restrict__ V, unsigned short* __restrict__ ws) {
    const int t = blockIdx.x * 256 + threadIdx.x;   // 0..655359
    if (t < 524288) {
        const int region = t >> 18;                 // 0=Q 1=K
        const int r = t & 262143;
        const int b = r >> 14;
        const int rem = r & 16383;
        const int t16 = rem >> 7;
        const int st  = (rem >> 6) & 1;
        const int l   = rem & 63;
        const int a = l & 15, g = l >> 4;
        const float* src = (region == 0 ? Q : K) +
            ((size_t)(b * SEQ + t16 * 16 + a)) * DIM + st * 32 + g * 8;
        const float s = (region == 0) ? QSCALE : 1.0f;
        short8 o;
        #pragma unroll
        for (int p = 0; p < 8; ++p) o[p] = (short)f2bf(src[p] * s);
        *(short8*)(ws + (size_t)region * 2097152 + (size_t)r * 8) = o;
    } else {
        const int r = t - 524288;                   // 0..131071 = [b][kt][l]
        const int b  = r >> 13;
        const int kt = (r >> 6) & 127;
        const int l  = r & 63;
        const int a = l & 15, g = l >> 4;
        const float* src = V + ((size_t)(b * SEQ + kt * 16 + g * 4)) * DIM + a;
        short8 o0, o1;
        #pragma unroll
        for (int dt = 0; dt < 2; ++dt)
            #pragma unroll
            for (int p = 0; p < 4; ++p)
                o0[dt * 4 + p] = (short)f2bf(src[(size_t)p * DIM + dt * 16]);
        #pragma unroll
        for (int dt = 2; dt < 4; ++dt)
            #pragma unroll
            for (int p = 0; p < 4; ++p)
                o1[(dt - 2) * 4 + p] = (short)f2bf(src[(size_t)p * DIM + dt * 16]);
        unsigned short* dst = ws + 4194304 + (size_t)r * 16;
        *(short8*)(dst)     = o0;
        *(short8*)(dst + 8) = o1;
    }
}

// ---------------- main: softmax-over-batch attention ----------------
// grid 1024 = 128 q-tiles(16) x 8 k-chunks(256).  ch = bx&7 -> chunk pinned to
// one XCD's L2 (512 KB K + 512 KB V resident). 4 blocks/CU = 16 waves/CU in 4
// independent barrier domains. block 256 = 4 waves = 4 batch-quarters.
// Swapped QK^T (mfma(K,Q)) puts P^T[k=g*4+r][q=a] in registers == the A-frag
// of 16x16x16 PV. Pipelined: K(it+1)/V(it) loads issue before the single
// barrier; only the softmax denominator crosses waves (double-buffered dl).
__global__ __launch_bounds__(256, 4)
void dpa_main(const unsigned short* __restrict__ Qw, const unsigned short* __restrict__ Kw,
              const unsigned short* __restrict__ Vw, float* __restrict__ Og) {
    __shared__ __align__(16) float dl[2][4][64][4];   // [buf][r][l][w-slot] : 8 KB

    const int tid = threadIdx.x;
    const int l = tid & 63;
    const int w = tid >> 6;            // batch-quarter 0..3
    const int a = l & 15, g = l >> 4;
    const int bx = blockIdx.x;
    const int ch = bx & 7;
    const int qt = bx >> 3;
    const int b0 = w * 4;
    const int wsw = w ^ ((l >> 3) & 3);   // swizzled slot: 2-way-free writes; sum perm-invariant

    // per-lane base pointers (element = ushort)
    const unsigned short* Qb = Qw + (size_t)b0 * 131072 + qt * 1024 + l * 8;
    const unsigned short* Kb = Kw + (size_t)b0 * 131072 + l * 8;
    const unsigned short* Vb = Vw + (size_t)b0 * 131072 + l * 16;

    // Q fragments in registers (iteration-invariant)
    short8 Qf[4][2];
    #pragma unroll
    for (int bb = 0; bb < 4; ++bb)
        #pragma unroll
        for (int st = 0; st < 2; ++st)
            Qf[bb][st] = *(const short8*)(Qb + bb * 131072 + st * 512);

    // prologue: K fragments for it=0
    short8 Kf[4][2];
    #pragma unroll
    for (int bb = 0; bb < 4; ++bb)
        #pragma unroll
        for (int st = 0; st < 2; ++st)
            Kf[bb][st] = *(const short8*)(Kb + bb * 131072 + (ch * 16) * 1024 + st * 512);

    floatx4 O[4][4];
    #pragma unroll
    for (int bb = 0; bb < 4; ++bb)
        #pragma unroll
        for (int dt = 0; dt < 4; ++dt) O[bb][dt] = (floatx4)0.0f;

    for (int it = 0; it < 16; ++it) {
        const int buf = it & 1;
        const int kt = ch * 16 + it;

        // ---- QK^T (swapped): S^T[k=g*4+r][q=a], scores pre-scaled via Q ----
        floatx4 S[4];
        __builtin_amdgcn_s_setprio(1);
        #pragma unroll
        for (int bb = 0; bb < 4; ++bb) {
            floatx4 s = (floatx4)0.0f;
            s = __builtin_amdgcn_mfma_f32_16x16x32_bf16(Kf[bb][0], Qf[bb][0], s, 0, 0, 0);
            s = __builtin_amdgcn_mfma_f32_16x16x32_bf16(Kf[bb][1], Qf[bb][1], s, 0, 0, 0);
            S[bb] = s;
        }
        __builtin_amdgcn_s_setprio(0);

        // ---- prefetch K(it+1): lands during softmax+barrier+PV ----
        const int ktn = (it < 15) ? (kt + 1) : kt;
        #pragma unroll
        for (int bb = 0; bb < 4; ++bb)
            #pragma unroll
            for (int st = 0; st < 2; ++st)
                Kf[bb][st] = *(const short8*)(Kb + bb * 131072 + ktn * 1024 + st * 512);

        // ---- V(it) loads: consumed only after the barrier ----
        short8 V01[4], V23[4];
        #pragma unroll
        for (int bb = 0; bb < 4; ++bb) {
            const unsigned short* vp = Vb + bb * 131072 + kt * 1024;
            V01[bb] = *(const short8*)(vp);
            V23[bb] = *(const short8*)(vp + 8);
        }

        // ---- local softmax partial (no max-subtraction: |S|<~10 in log2 domain) ----
        #pragma unroll
        for (int r = 0; r < 4; ++r) {
            float e0 = EXP2(S[0][r]);
            float e1 = EXP2(S[1][r]);
            float e2 = EXP2(S[2][r]);
            float e3 = EXP2(S[3][r]);
            S[0][r] = e0; S[1][r] = e1; S[2][r] = e2; S[3][r] = e3;
            dl[buf][r][l][wsw] = (e0 + e1) + (e2 + e3);
        }
        __syncthreads();

        // ---- combine denominators (1 x b128 per r, conflict-free) ----
        float fr[4];
        #pragma unroll
        for (int r = 0; r < 4; ++r) {
            const floatx4 t = *(const floatx4*)&dl[buf][r][l][0];
            fr[r] = __builtin_amdgcn_rcpf((t[0] + t[1]) + (t[2] + t[3]));
        }

        // ---- finalize P (bf16 pack via round+perm) + PV ----
        #pragma unroll
        for (int bb = 0; bb < 4; ++bb) {
            const unsigned int c0 = __builtin_bit_cast(unsigned int, S[bb][0] * fr[0]) + 0x8000u;
            const unsigned int c1 = __builtin_bit_cast(unsigned int, S[bb][1] * fr[1]) + 0x8000u;
            const unsigned int c2 = __builtin_bit_cast(unsigned int, S[bb][2] * fr[2]) + 0x8000u;
            const unsigned int c3 = __builtin_bit_cast(unsigned int, S[bb][3] * fr[3]) + 0x8000u;
            int2v pp;
            pp[0] = (int)__builtin_amdgcn_perm(c1, c0, 0x07060302u);
            pp[1] = (int)__builtin_amdgcn_perm(c3, c2, 0x07060302u);
            const short4v af = __builtin_bit_cast(short4v, pp);

            const short4v vb0 = __builtin_shufflevector(V01[bb], V01[bb], 0, 1, 2, 3);
            const short4v vb1 = __builtin_shufflevector(V01[bb], V01[bb], 4, 5, 6, 7);
            const short4v vb2 = __builtin_shufflevector(V23[bb], V23[bb], 0, 1, 2, 3);
            const short4v vb3 = __builtin_shufflevector(V23[bb], V23[bb], 4, 5, 6, 7);

            __builtin_amdgcn_s_setprio(1);
            O[bb][0] = MFMA16(af, vb0, O[bb][0]);
            O[bb][1] = MFMA16(af, vb1, O[bb][1]);
            O[bb][2] = MFMA16(af, vb2, O[bb][2]);
            O[bb][3] = MFMA16(af, vb3, O[bb][3]);
            __builtin_amdgcn_s_setprio(0);
        }
        // single barrier/iter; dl double-buffer makes next-iter writes safe
    }

    // guard MFMA->VALU read (needed for asm fallback; cheap otherwise)
    asm volatile("s_nop 7\n\ts_nop 7" :::);

    // ---- merge k-chunk partials ----
    #pragma unroll
    for (int bb = 0; bb < 4; ++bb)
        #pragma unroll
        for (int dt = 0; dt < 4; ++dt)
            #pragma unroll
            for (int r = 0; r < 4; ++r)
                unsafeAtomicAdd(Og + ((size_t)((b0 + bb) * SEQ + qt * 16 + g * 4 + r)) * DIM
                                    + dt * 16 + a,
                                O[bb][dt][r]);
}

// ---------------- fallback (ws too small): naive fp32 ----------------
__global__ __launch_bounds__(512)
void dpa_naive(const float* __restrict__ Q, const float* __restrict__ K,
               const float* __restrict__ V, float* __restrict__ out) {
    __shared__ float attn_lds[BATCH][8][64];
    const int tid = threadIdx.x;
    const int lane_k = tid & 63, row_q = tid >> 6, lane_d = tid & 63;
    const int q0 = blockIdx.x * 8;
    float acc[BATCH];
    #pragma unroll
    for (int b = 0; b < BATCH; ++b) acc[b] = 0.0f;
    for (int k0 = 0; k0 < SEQ; k0 += 64) {
        float s[BATCH];
        #pragma unroll
        for (int b = 0; b < BATCH; ++b) {
            const float4* qrow = (const float4*)(Q + ((size_t)b * SEQ + (q0 + row_q)) * DIM);
            const float4* krow = (const float4*)(K + ((size_t)b * SEQ + (k0 + lane_k)) * DIM);
            float a0 = 0.f;
            #pragma unroll
            for (int d4 = 0; d4 < 16; ++d4) {
                float4 qa = qrow[d4]; float4 kb = krow[d4];
                a0 += qa.x*kb.x + qa.y*kb.y + qa.z*kb.z + qa.w*kb.w;
            }
            s[b] = a0 * 0.125f;
        }
        float m = s[0];
        #pragma unroll
        for (int b = 1; b < BATCH; ++b) m = fmaxf(m, s[b]);
        float den = 0.f;
        #pragma unroll
        for (int b = 0; b < BATCH; ++b) { s[b] = __expf(s[b] - m); den += s[b]; }
        const float inv = 1.0f / den;
        #pragma unroll
        for (int b = 0; b < BATCH; ++b) attn_lds[b][row_q][lane_k] = s[b] * inv;
        __syncthreads();
        #pragma unroll
        for (int b = 0; b < BATCH; ++b) {
            const float* vbase = V + ((size_t)b * SEQ + k0) * DIM + lane_d;
            float acc2 = 0.f;
            #pragma unroll 8
            for (int kk = 0; kk < 64; ++kk) acc2 += attn_lds[b][row_q][kk] * vbase[(size_t)kk * DIM];
            acc[b] += acc2;
        }
        __syncthreads();
    }
    #pragma unroll
    for (int b = 0; b < BATCH; ++b)
        out[((size_t)b * SEQ + (q0 + row_q)) * DIM + lane_d] = acc[b];
}

extern "C" void kernel_launch(void* const* d_in, const int* in_sizes, int n_in,
                              void* d_out, int out_size, void* d_ws, size_t ws_size,
                              hipStream_t stream) {
    const float* Q = (const float*)d_in[0];
    const float* K = (const float*)d_in[1];
    const float* V = (const float*)d_in[2];
    float* out = (float*)d_out;

    if (ws_size < WS_NEED) {
        dpa_naive<<<dim3(SEQ / 8), dim3(512), 0, stream>>>(Q, K, V, out);
        return;
    }
    unsigned short* ws = (unsigned short*)d_ws;
    hipMemsetAsync(d_out, 0, (size_t)out_size * sizeof(float), stream);
    convert_kernel<<<dim3(2560), dim3(256), 0, stream>>>(Q, K, V, ws);
    dpa_main<<<dim3(1024), dim3(256), 0, stream>>>(ws, ws + 2097152, ws + 4194304, out);
}

// Round 7
// 81.928 us; speedup vs baseline: 3.3252x; 3.3252x over previous
//
#include <hip/hip_runtime.h>
#include <hip/hip_bf16.h>

typedef __attribute__((ext_vector_type(8))) short short8;
typedef __attribute__((ext_vector_type(4))) short short4v;
typedef __attribute__((ext_vector_type(2))) int   int2v;
typedef __attribute__((ext_vector_type(4))) float floatx4;

#define BATCH 16
#define SEQ   2048
#define DIM   64
#define QSCALE 0.18033688011112042f   /* 0.125 * log2(e) : softmax in exp2 domain */
#define WS_NEED (12u*1024u*1024u)

__device__ __forceinline__ unsigned short f2bf(float f) {
    return __builtin_bit_cast(unsigned short, __float2bfloat16(f));
}

// raw v_exp_f32 (exp2)
#if defined(__has_builtin)
#if __has_builtin(__builtin_amdgcn_exp2f)
#define EXP2(x) __builtin_amdgcn_exp2f(x)
#endif
#endif
#ifndef EXP2
#define EXP2(x) exp2f(x)
#endif

// ---- K=16 bf16 MFMA ----
#if defined(__has_builtin)
#if __has_builtin(__builtin_amdgcn_mfma_f32_16x16x16bf16_1k)
#define MFMA16(A,B,C) __builtin_amdgcn_mfma_f32_16x16x16bf16_1k(A,B,C,0,0,0)
#elif __has_builtin(__builtin_amdgcn_mfma_f32_16x16x16_bf16)
#define MFMA16(A,B,C) __builtin_amdgcn_mfma_f32_16x16x16_bf16(A,B,C,0,0,0)
#endif
#endif
#ifndef MFMA16
__device__ __forceinline__ floatx4 mfma16_asm(short4v a, short4v b, floatx4 c) {
    asm volatile("s_nop 1\n\tv_mfma_f32_16x16x16_bf16 %0, %1, %2, %0"
                 : "+v"(c) : "v"(a), "v"(b));
    return c;
}
#define MFMA16(A,B,C) mfma16_asm(A,B,C)
#endif

// ---------------- convert: fp32 -> bf16 MFMA-frag layouts ----------------
// Qw [16][128 t16][2 st][64 l][8p] = Q[b][t16*16+a][st*32+g*8+p] * QSCALE  (a=l&15,g=l>>4)
// Kw same (scale 1).
// Vw [16][128 kt][64 l][4 dt][4p] = V[b][kt*16+g*4+p][dt*16+a]   (B frag for 16x16x16)
__global__ __launch_bounds__(256)
void convert_kernel(const float* __restrict__ Q, const float* __restrict__ K,
                    const float* __restrict__ V, unsigned short* __restrict__ ws) {
    const int t = blockIdx.x * 256 + threadIdx.x;   // 0..655359
    if (t < 524288) {
        const int region = t >> 18;                 // 0=Q 1=K
        const int r = t & 262143;
        const int b = r >> 14;
        const int rem = r & 16383;
        const int t16 = rem >> 7;
        const int st  = (rem >> 6) & 1;
        const int l   = rem & 63;
        const int a = l & 15, g = l >> 4;
        const float* src = (region == 0 ? Q : K) +
            ((size_t)(b * SEQ + t16 * 16 + a)) * DIM + st * 32 + g * 8;
        const float s = (region == 0) ? QSCALE : 1.0f;
        short8 o;
        #pragma unroll
        for (int p = 0; p < 8; ++p) o[p] = (short)f2bf(src[p] * s);
        *(short8*)(ws + (size_t)region * 2097152 + (size_t)r * 8) = o;
    } else {
        const int r = t - 524288;                   // 0..131071 = [b][kt][l]
        const int b  = r >> 13;
        const int kt = (r >> 6) & 127;
        const int l  = r & 63;
        const int a = l & 15, g = l >> 4;
        const float* src = V + ((size_t)(b * SEQ + kt * 16 + g * 4)) * DIM + a;
        short8 o0, o1;
        #pragma unroll
        for (int dt = 0; dt < 2; ++dt)
            #pragma unroll
            for (int p = 0; p < 4; ++p)
                o0[dt * 4 + p] = (short)f2bf(src[(size_t)p * DIM + dt * 16]);
        #pragma unroll
        for (int dt = 2; dt < 4; ++dt)
            #pragma unroll
            for (int p = 0; p < 4; ++p)
                o1[(dt - 2) * 4 + p] = (short)f2bf(src[(size_t)p * DIM + dt * 16]);
        unsigned short* dst = ws + 4194304 + (size_t)r * 16;
        *(short8*)(dst)     = o0;
        *(short8*)(dst + 8) = o1;
    }
}

// ---------------- main: softmax-over-batch attention ----------------
// grid 512 = 128 q-tiles(16) x 4 k-chunks(512). block 512 = 8 waves = 8
// batch-PAIRS (2 batches/wave -> ~115 regs/wave incl. accs, fits the 128
// bucket -> 16 waves/CU, 2 barrier domains). Swapped QK^T (mfma(K,Q)) puts
// P^T[k=g*4+r][q=a] in registers == the A-frag of 16x16x16 PV. Pipelined:
// K(it+1)/V(it) loads issue before the single barrier; only the softmax
// denominator crosses waves (dl[2][4][64][8], write slot w^(l>>3) -> 2-way
// free; read 2x b128, sum is slot-permutation-invariant).
__global__ __launch_bounds__(512)
void dpa_main(const unsigned short* __restrict__ Qw, const unsigned short* __restrict__ Kw,
              const unsigned short* __restrict__ Vw, float* __restrict__ Og) {
    __shared__ __align__(16) float dl[2][4][64][8];   // 16 KB

    const int tid = threadIdx.x;
    const int l = tid & 63;
    const int w = tid >> 6;            // batch-pair 0..7
    const int a = l & 15, g = l >> 4;
    const int bx = blockIdx.x;
    const int ch = bx & 3;
    const int qt = bx >> 2;
    const int b0 = w * 2;
    const int wsw = w ^ (l >> 3);      // slot swizzle: 2-way bank aliasing (free)

    // per-lane base pointers (element = ushort)
    const unsigned short* Kb = Kw + (size_t)b0 * 131072 + l * 8;
    const unsigned short* Vb = Vw + (size_t)b0 * 131072 + l * 16;

    // Q fragments in registers (iteration-invariant)
    short8 Qf[2][2];
    {
        const unsigned short* Qb = Qw + (size_t)b0 * 131072 + qt * 1024 + l * 8;
        #pragma unroll
        for (int bb = 0; bb < 2; ++bb)
            #pragma unroll
            for (int st = 0; st < 2; ++st)
                Qf[bb][st] = *(const short8*)(Qb + bb * 131072 + st * 512);
    }

    // prologue: K fragments for it=0
    short8 Kf[2][2];
    #pragma unroll
    for (int bb = 0; bb < 2; ++bb)
        #pragma unroll
        for (int st = 0; st < 2; ++st)
            Kf[bb][st] = *(const short8*)(Kb + bb * 131072 + (ch * 32) * 1024 + st * 512);

    floatx4 O[2][4];
    #pragma unroll
    for (int bb = 0; bb < 2; ++bb)
        #pragma unroll
        for (int dt = 0; dt < 4; ++dt) O[bb][dt] = (floatx4)0.0f;

    #pragma unroll 2
    for (int it = 0; it < 32; ++it) {
        const int buf = it & 1;
        const int kt = ch * 32 + it;

        // ---- QK^T (swapped): S^T[k=g*4+r][q=a], scores pre-scaled via Q ----
        floatx4 S[2];
        __builtin_amdgcn_s_setprio(1);
        #pragma unroll
        for (int bb = 0; bb < 2; ++bb) {
            floatx4 s = (floatx4)0.0f;
            s = __builtin_amdgcn_mfma_f32_16x16x32_bf16(Kf[bb][0], Qf[bb][0], s, 0, 0, 0);
            s = __builtin_amdgcn_mfma_f32_16x16x32_bf16(Kf[bb][1], Qf[bb][1], s, 0, 0, 0);
            S[bb] = s;
        }
        __builtin_amdgcn_s_setprio(0);

        // ---- prefetch K(it+1): lands during softmax+barrier+PV ----
        const int ktn = (it < 31) ? (kt + 1) : kt;
        #pragma unroll
        for (int bb = 0; bb < 2; ++bb)
            #pragma unroll
            for (int st = 0; st < 2; ++st)
                Kf[bb][st] = *(const short8*)(Kb + bb * 131072 + ktn * 1024 + st * 512);

        // ---- V(it) loads: consumed only after the barrier ----
        short8 V01[2], V23[2];
        #pragma unroll
        for (int bb = 0; bb < 2; ++bb) {
            const unsigned short* vp = Vb + bb * 131072 + kt * 1024;
            V01[bb] = *(const short8*)(vp);
            V23[bb] = *(const short8*)(vp + 8);
        }

        // ---- local softmax partial (no max-subtraction: |S|<~10 in log2 domain) ----
        #pragma unroll
        for (int r = 0; r < 4; ++r) {
            float e0 = EXP2(S[0][r]);
            float e1 = EXP2(S[1][r]);
            S[0][r] = e0; S[1][r] = e1;
            dl[buf][r][l][wsw] = e0 + e1;
        }
        __syncthreads();

        // ---- combine denominators (2 x b128 per r, linear sweep) ----
        float fr[4];
        #pragma unroll
        for (int r = 0; r < 4; ++r) {
            const floatx4 t0 = *(const floatx4*)&dl[buf][r][l][0];
            const floatx4 t1 = *(const floatx4*)&dl[buf][r][l][4];
            const floatx4 ts = t0 + t1;
            fr[r] = __builtin_amdgcn_rcpf((ts[0] + ts[1]) + (ts[2] + ts[3]));
        }

        // ---- finalize P (bf16 pack via round+perm) + PV ----
        #pragma unroll
        for (int bb = 0; bb < 2; ++bb) {
            const unsigned int c0 = __builtin_bit_cast(unsigned int, S[bb][0] * fr[0]) + 0x8000u;
            const unsigned int c1 = __builtin_bit_cast(unsigned int, S[bb][1] * fr[1]) + 0x8000u;
            const unsigned int c2 = __builtin_bit_cast(unsigned int, S[bb][2] * fr[2]) + 0x8000u;
            const unsigned int c3 = __builtin_bit_cast(unsigned int, S[bb][3] * fr[3]) + 0x8000u;
            int2v pp;
            pp[0] = (int)__builtin_amdgcn_perm(c1, c0, 0x07060302u);
            pp[1] = (int)__builtin_amdgcn_perm(c3, c2, 0x07060302u);
            const short4v af = __builtin_bit_cast(short4v, pp);

            const short4v vb0 = __builtin_shufflevector(V01[bb], V01[bb], 0, 1, 2, 3);
            const short4v vb1 = __builtin_shufflevector(V01[bb], V01[bb], 4, 5, 6, 7);
            const short4v vb2 = __builtin_shufflevector(V23[bb], V23[bb], 0, 1, 2, 3);
            const short4v vb3 = __builtin_shufflevector(V23[bb], V23[bb], 4, 5, 6, 7);

            __builtin_amdgcn_s_setprio(1);
            O[bb][0] = MFMA16(af, vb0, O[bb][0]);
            O[bb][1] = MFMA16(af, vb1, O[bb][1]);
            O[bb][2] = MFMA16(af, vb2, O[bb][2]);
            O[bb][3] = MFMA16(af, vb3, O[bb][3]);
            __builtin_amdgcn_s_setprio(0);
        }
        // single barrier/iter; dl double-buffer makes next-iter writes safe
    }

    // guard MFMA->VALU read (needed for asm fallback; cheap otherwise)
    asm volatile("s_nop 7\n\ts_nop 7" :::);

    // ---- merge k-chunk partials ----
    #pragma unroll
    for (int bb = 0; bb < 2; ++bb)
        #pragma unroll
        for (int dt = 0; dt < 4; ++dt)
            #pragma unroll
            for (int r = 0; r < 4; ++r)
                unsafeAtomicAdd(Og + ((size_t)((b0 + bb) * SEQ + qt * 16 + g * 4 + r)) * DIM
                                    + dt * 16 + a,
                                O[bb][dt][r]);
}

// ---------------- fallback (ws too small): naive fp32 ----------------
__global__ __launch_bounds__(512)
void dpa_naive(const float* __restrict__ Q, const float* __restrict__ K,
               const float* __restrict__ V, float* __restrict__ out) {
    __shared__ float attn_lds[BATCH][8][64];
    const int tid = threadIdx.x;
    const int lane_k = tid & 63, row_q = tid >> 6, lane_d = tid & 63;
    const int q0 = blockIdx.x * 8;
    float acc[BATCH];
    #pragma unroll
    for (int b = 0; b < BATCH; ++b) acc[b] = 0.0f;
    for (int k0 = 0; k0 < SEQ; k0 += 64) {
        float s[BATCH];
        #pragma unroll
        for (int b = 0; b < BATCH; ++b) {
            const float4* qrow = (const float4*)(Q + ((size_t)b * SEQ + (q0 + row_q)) * DIM);
            const float4* krow = (const float4*)(K + ((size_t)b * SEQ + (k0 + lane_k)) * DIM);
            float a0 = 0.f;
            #pragma unroll
            for (int d4 = 0; d4 < 16; ++d4) {
                float4 qa = qrow[d4]; float4 kb = krow[d4];
                a0 += qa.x*kb.x + qa.y*kb.y + qa.z*kb.z + qa.w*kb.w;
            }
            s[b] = a0 * 0.125f;
        }
        float m = s[0];
        #pragma unroll
        for (int b = 1; b < BATCH; ++b) m = fmaxf(m, s[b]);
        float den = 0.f;
        #pragma unroll
        for (int b = 0; b < BATCH; ++b) { s[b] = __expf(s[b] - m); den += s[b]; }
        const float inv = 1.0f / den;
        #pragma unroll
        for (int b = 0; b < BATCH; ++b) attn_lds[b][row_q][lane_k] = s[b] * inv;
        __syncthreads();
        #pragma unroll
        for (int b = 0; b < BATCH; ++b) {
            const float* vbase = V + ((size_t)b * SEQ + k0) * DIM + lane_d;
            float acc2 = 0.f;
            #pragma unroll 8
            for (int kk = 0; kk < 64; ++kk) acc2 += attn_lds[b][row_q][kk] * vbase[(size_t)kk * DIM];
            acc[b] += acc2;
        }
        __syncthreads();
    }
    #pragma unroll
    for (int b = 0; b < BATCH; ++b)
        out[((size_t)b * SEQ + (q0 + row_q)) * DIM + lane_d] = acc[b];
}

extern "C" void kernel_launch(void* const* d_in, const int* in_sizes, int n_in,
                              void* d_out, int out_size, void* d_ws, size_t ws_size,
                              hipStream_t stream) {
    const float* Q = (const float*)d_in[0];
    const float* K = (const float*)d_in[1];
    const float* V = (const float*)d_in[2];
    float* out = (float*)d_out;

    if (ws_size < WS_NEED) {
        dpa_naive<<<dim3(SEQ / 8), dim3(512), 0, stream>>>(Q, K, V, out);
        return;
    }
    unsigned short* ws = (unsigned short*)d_ws;
    hipMemsetAsync(d_out, 0, (size_t)out_size * sizeof(float), stream);
    convert_kernel<<<dim3(2560), dim3(256), 0, stream>>>(Q, K, V, ws);
    dpa_main<<<dim3(512), dim3(512), 0, stream>>>(ws, ws + 2097152, ws + 4194304, out);
}